// Round 2
// baseline (3756.097 us; speedup 1.0000x reference)
//
#include <hip/hip_runtime.h>

#define NN   6144
#define MP1  6145
#define KC   4              // columns per lane
#define WCH  (KC * 64)      // columns per wave = 256
#define GCH  (NN / WCH)     // 24 waves / workgroups
#define RT   16             // rows per inter-wave handoff tile
#define FINF 99999.0f

__device__ __forceinline__ float readlane_f(float v, int l) {
    return __int_as_float(__builtin_amdgcn_readlane(__float_as_int(v), l));
}

// Lane-systolic DTW. Wave g owns columns [g*WCH,(g+1)*WCH); lane l owns KC
// contiguous columns and processes row (s-l) at step s.
// Steady-state loop has ZERO global loads: x rides the lane stagger via
// shfl_up (lane0 injects x[s] by uniform readlane from a register window),
// carries move via one shfl_up; cross-wave boundary carries are staged RAW
// in d_ws (or re-squared from out[] if ws too small) once per RT steps.
__global__ void __launch_bounds__(64) dtw_main(const float* __restrict__ x,
                                               const float* __restrict__ y,
                                               float* __restrict__ out,
                                               int* __restrict__ flags,
                                               float* __restrict__ bnd) {
    const int g    = blockIdx.x;
    const int lane = threadIdx.x;
    const int j0   = g * WCH;          // wave's first y-column
    const int c0   = j0 + lane * KC;   // lane's first y-column

    float yv[KC], prev[KC];
#pragma unroll
    for (int q = 0; q < KC; ++q) {
        yv[q]   = y[c0 + q];
        prev[q] = FINF;                // dtw[0][col] = INF
    }
    float pl    = (c0 == 0) ? 0.0f : FINF;  // diag seed: dtw[0][0]=0
    float rlast = FINF;                // my segment-end r, previous step
    float vbuf  = FINF;                // lane j<RT: left-boundary carry row tile+j
    float xv    = x[0];                // my current x value (valid once active)

    // x register window, double-buffered: xbuf = x[w*64 + lane]
    int xi0 = lane;           if (xi0 > NN - 1) xi0 = NN - 1;
    int xi1 = 64 + lane;      if (xi1 > NN - 1) xi1 = NN - 1;
    float xbuf  = x[xi0];
    float xbufN = x[xi1];

    int off = (1 - lane) * MP1 + c0 + 1;   // &out[row i+1][c0+1], i = s-lane

    for (int s = 0; s < NN + 63; ++s) {
        const int i = s - lane;

        // ---- refill x window every 64 steps (64-step prefetch slack) ----
        if ((s & 63) == 0 && s != 0) {
            xbuf = xbufN;
            int idx = s + 64 + lane;
            if (idx > NN - 1) idx = NN - 1;
            xbufN = x[idx];
        }

        // ---- consumer: fetch RT left-boundary carries at tile start ----
        if (g != 0 && (s & (RT - 1)) == 0 && s < NN) {
            const int want = (s / RT) + 1;
            while (__hip_atomic_load(&flags[(g - 1) * 16], __ATOMIC_ACQUIRE,
                                     __HIP_MEMORY_SCOPE_AGENT) < want) {
                __builtin_amdgcn_s_sleep(8);
            }
            float tv = FINF;
            if (bnd) {
                if (lane < RT) tv = bnd[(size_t)(g - 1) * NN + s + lane]; // raw
            } else {
                if (lane < RT) {
                    tv = out[(size_t)(s + lane + 1) * MP1 + j0];          // sqrt'd
                    tv = tv * tv;
                }
            }
            vbuf = tv;
        }

        // ---- per-step carries: one lgkmcnt wait covers both bpermutes ----
        const float up   = __shfl_up(rlast, 1);           // left lane's r, same row
        const float xup  = __shfl_up(xv, 1);              // left lane's x, same row
        const float vcar = readlane_f(vbuf, s & (RT - 1)); // uniform: scalar bcast
        const float xnew = readlane_f(xbuf, s & 63);       // x[s], scalar bcast

        const float v = (lane == 0) ? ((g == 0) ? FINF : vcar) : up;
        xv            = (lane == 0) ? xnew : xup;
        const float xi = xv;

        // costs off the carry chain
        float c[KC];
#pragma unroll
        for (int q = 0; q < KC; ++q) { const float d = xi - yv[q]; c[q] = d * d; }

        // ---- KC serial cells: r = c + min3(left, up, diag) ----
        float r = v, pm1 = pl;
        float nv[KC];
#pragma unroll
        for (int q = 0; q < KC; ++q) {
            r     = c[q] + fminf(fminf(r, prev[q]), pm1);  // v_min3 + v_add
            pm1   = prev[q];
            nv[q] = r;
        }

        const bool active = (i >= 0) && (i < NN);
        if (active) {
#pragma unroll
            for (int q = 0; q < KC; ++q) {
                prev[q] = nv[q];
                __builtin_nontemporal_store(__builtin_amdgcn_sqrtf(nv[q]),
                                            &out[off + q]);
            }
            rlast = r;
            pl    = v;
            if (bnd != nullptr && lane == 63)
                bnd[(size_t)g * NN + i] = r;               // raw boundary carry
        }
        off += MP1;

        // ---- producer: publish flag every RT completed boundary rows ----
        const int done = s - 62;   // rows fully completed by lane 63
        if (g != GCH - 1 && done > 0 && (done & (RT - 1)) == 0) {
            __threadfence();       // agent-scope release of bnd/out stores
            if (lane == 0)
                __hip_atomic_store(&flags[g * 16], done / RT, __ATOMIC_RELEASE,
                                   __HIP_MEMORY_SCOPE_AGENT);
        }
    }
}

// Row 0 and column 0 sentinels: sqrt(INF), with out[0,0] = 0.
__global__ void dtw_edges(float* __restrict__ out) {
    const int idx = blockIdx.x * blockDim.x + threadIdx.x;
    const float e = __builtin_amdgcn_sqrtf(FINF);
    if (idx <= NN) {
        out[idx] = (idx == 0) ? 0.0f : e;           // row 0
        if (idx >= 1) out[(size_t)idx * MP1] = e;   // column 0
    }
}

extern "C" void kernel_launch(void* const* d_in, const int* in_sizes, int n_in,
                              void* d_out, int out_size, void* d_ws, size_t ws_size,
                              hipStream_t stream) {
    (void)in_sizes; (void)n_in; (void)out_size;
    const float* x = (const float*)d_in[0];
    const float* y = (const float*)d_in[1];
    float* out     = (float*)d_out;
    int* flags     = (int*)d_ws;

    // raw boundary staging in d_ws if it fits (4 KB flags pad + 24*6144 floats)
    const size_t bnd_off    = 4096;
    const size_t bnd_needed = bnd_off + (size_t)GCH * NN * sizeof(float);
    float* bnd = (ws_size >= bnd_needed) ? (float*)((char*)d_ws + bnd_off)
                                         : nullptr;

    // flags must start at 0 every call (d_ws is re-poisoned to 0xAA)
    hipMemsetAsync(flags, 0, GCH * 16 * sizeof(int), stream);
    dtw_edges<<<(MP1 + 255) / 256, 256, 0, stream>>>(out);
    dtw_main<<<GCH, 64, 0, stream>>>(x, y, out, flags, bnd);
}

// Round 3
// 2337.002 us; speedup vs baseline: 1.6072x; 1.6072x over previous
//
#include <hip/hip_runtime.h>

#define NN    6144
#define MP1   6145
#define R     4                 // rows per lane per step
#define KC    4                 // columns per lane
#define WCH   (KC * 64)         // 256 columns per wave
#define GCH   (NN / WCH)        // 24 waves / workgroups
#define RTS   8                 // steps per handoff tile (= 32 rows)
#define NWS   (NN / R)          // 1536 working steps per wave
#define STEPS (NWS + 63)        // + lane-stagger fill
#define FINF  99999.0f

__device__ __forceinline__ float readlane_f(float v, int l) {
    return __int_as_float(__builtin_amdgcn_readlane(__float_as_int(v), l));
}

// Lane-systolic DTW, R=4 rows per step. Wave g owns columns [g*WCH,(g+1)*WCH);
// lane l owns KC contiguous columns and processes table rows R*(s-l)+1..+R at
// step s. Cross-lane carries (R right-edge values) and x values move by one
// shfl_up per row per step; costs (x-y)^2 for step s+1 are precomputed at the
// end of step s so the in-step critical path is shfl-wait + 7 dependent
// min3/add pairs. Cross-wave boundary carries staged RAW in d_ws (float4),
// 32 rows per flag; fallback reads sqrt'd values from out[] and re-squares.
__global__ void __launch_bounds__(64) dtw_main(const float* __restrict__ x,
                                               const float* __restrict__ y,
                                               float* __restrict__ out,
                                               int* __restrict__ flags,
                                               float* __restrict__ bnd) {
    const int g    = blockIdx.x;
    const int lane = threadIdx.x;
    const int j0   = g * WCH;           // wave's first column (table col index)
    const int c0   = j0 + lane * KC;    // lane's first column

    float yv[KC], cur[KC];
#pragma unroll
    for (int q = 0; q < KC; ++q) {
        yv[q]  = y[c0 + q];
        cur[q] = FINF;                  // dtw[0][col] = INF
    }
    float pl = (c0 == 0) ? 0.0f : FINF; // diag seed: dtw[0][0] = 0
    float rlast[R];
#pragma unroll
    for (int r = 0; r < R; ++r) rlast[r] = FINF;
    float vbuf = FINF;

    // x register windows (double-buffered): xw = x[4*(w*64+lane) .. +3]
    const float4* x4 = (const float4*)x;
    float4 xw  = x4[lane];              // rows 0..255
    float4 xwN = x4[64 + lane];         // rows 256..511
    float xcur[R];
#pragma unroll
    for (int r = 0; r < R; ++r) xcur[r] = x[r];   // valid for lane 0 at s=0

    // costs for the CURRENT step (precomputed each iteration for the next)
    float cnx[R][KC];
#pragma unroll
    for (int r = 0; r < R; ++r)
#pragma unroll
        for (int q = 0; q < KC; ++q) {
            const float d = xcur[r] - yv[q];
            cnx[r][q] = d * d;
        }

    int off = (1 - R * lane) * MP1 + c0 + 1;   // &out[R*(s-lane)+1][c0+1]

    for (int s = 0; s < STEPS; ++s) {
        // ---- consumer: fetch 32 left-boundary rows at tile start ----
        if (g != 0 && s < NWS && (s & (RTS - 1)) == 0) {
            const int want = (s >> 3) + 1;
            while (__hip_atomic_load(&flags[(g - 1) * 16], __ATOMIC_ACQUIRE,
                                     __HIP_MEMORY_SCOPE_AGENT) < want) {
                __builtin_amdgcn_s_sleep(8);
            }
            float tv = FINF;
            if (bnd) {
                if (lane < 32) tv = bnd[(size_t)(g - 1) * NN + R * s + lane];
            } else {
                if (lane < 32) {
                    const float t = out[(size_t)(R * s + 1 + lane) * MP1 + j0];
                    tv = t * t;
                }
            }
            vbuf = tv;
        }

        // ---- carries for this step: shfl_up of last step's right edges ----
        float vin[R];
#pragma unroll
        for (int r = 0; r < R; ++r) {
            const float up = __shfl_up(rlast[r], 1);
            const float vb = readlane_f(vbuf, ((s & (RTS - 1)) << 2) + r);
            const float l0 = (g == 0) ? FINF : vb;
            vin[r] = (lane == 0) ? l0 : up;
        }

        const bool active = (s >= lane) && (s - lane < NWS);
        if (active) {
            // ---- R x KC tile: r_new = c + min3(left, up, diag) ----
#pragma unroll
            for (int r = 0; r < R; ++r) {
                float rl  = vin[r];
                float pm1 = (r == 0) ? pl : vin[r - 1];
                float nv[KC];
#pragma unroll
                for (int q = 0; q < KC; ++q) {
                    const float upv = cur[q];
                    rl     = cnx[r][q] + fminf(fminf(rl, upv), pm1);
                    pm1    = upv;
                    cur[q] = rl;
                    nv[q]  = rl;
                }
                rlast[r] = rl;
#pragma unroll
                for (int q = 0; q < KC; ++q)
                    out[off + r * MP1 + q] = __builtin_amdgcn_sqrtf(nv[q]);
            }
            pl = vin[R - 1];
            if (bnd && lane == 63) {
                float4 v4 = make_float4(rlast[0], rlast[1], rlast[2], rlast[3]);
                *(float4*)&bnd[(size_t)g * NN + R * (s - 63)] = v4;
            }
        }
        off += R * MP1;

        // ---- x for next step (off the carry chain) ----
        const int sn = s + 1;
        if ((sn & 63) == 0) {           // window rollover + prefetch
            xw = xwN;
            int nb = R * sn + 256 + R * lane;
            if (nb > NN - R) nb = NN - R;
            xwN = x4[nb >> 2];
        }
        const float* xwp = (const float*)&xw;
#pragma unroll
        for (int r = 0; r < R; ++r) {
            const float xs = __shfl_up(xcur[r], 1);
            const float xj = readlane_f(xwp[r], sn & 63);
            xcur[r] = (lane == 0) ? xj : xs;
        }
#pragma unroll
        for (int r = 0; r < R; ++r)
#pragma unroll
            for (int q = 0; q < KC; ++q) {
                const float d = xcur[r] - yv[q];
                cnx[r][q] = d * d;
            }

        // ---- producer: publish every 32 completed boundary rows ----
        if (g != GCH - 1 && s > 62 && ((s - 62) & (RTS - 1)) == 0) {
            __threadfence();            // make bnd/out stores agent-visible
            if (lane == 0)
                __hip_atomic_store(&flags[g * 16], (s - 62) >> 3,
                                   __ATOMIC_RELEASE, __HIP_MEMORY_SCOPE_AGENT);
        }
    }
}

// Row 0 and column 0 sentinels: sqrt(INF), with out[0,0] = 0.
__global__ void dtw_edges(float* __restrict__ out) {
    const int idx = blockIdx.x * blockDim.x + threadIdx.x;
    const float e = __builtin_amdgcn_sqrtf(FINF);
    if (idx <= NN) {
        out[idx] = (idx == 0) ? 0.0f : e;           // row 0
        if (idx >= 1) out[(size_t)idx * MP1] = e;   // column 0
    }
}

extern "C" void kernel_launch(void* const* d_in, const int* in_sizes, int n_in,
                              void* d_out, int out_size, void* d_ws, size_t ws_size,
                              hipStream_t stream) {
    (void)in_sizes; (void)n_in; (void)out_size;
    const float* x = (const float*)d_in[0];
    const float* y = (const float*)d_in[1];
    float* out     = (float*)d_out;
    int* flags     = (int*)d_ws;

    // raw boundary staging in d_ws if it fits (4 KB flag pad + 24*6144 floats)
    const size_t bnd_off    = 4096;
    const size_t bnd_needed = bnd_off + (size_t)GCH * NN * sizeof(float);
    float* bnd = (ws_size >= bnd_needed) ? (float*)((char*)d_ws + bnd_off)
                                         : nullptr;

    hipMemsetAsync(flags, 0, GCH * 16 * sizeof(int), stream);
    dtw_edges<<<(MP1 + 255) / 256, 256, 0, stream>>>(out);
    dtw_main<<<GCH, 64, 0, stream>>>(x, y, out, flags, bnd);
}

// Round 4
// 2064.283 us; speedup vs baseline: 1.8196x; 1.1321x over previous
//
#include <hip/hip_runtime.h>
#include <math.h>

#define NN    6144
#define MP1   6145
#define R     4                  // rows per lane per step
#define KC    4                  // columns per lane
#define WCH   (KC * 64)          // 256 columns per wave
#define GCH   (NN / WCH)         // 24 waves / workgroups
#define RTS   8                  // steps per handoff tile (= 32 rows)
#define NWS   (NN / R)           // 1536 working steps per wave
#define STEPS (NWS + 63)         // + lane-stagger fill = 1599
#define FINF  99999.0f

typedef float f4a __attribute__((ext_vector_type(4), aligned(4)));   // unaligned-ok store
typedef float f4v __attribute__((ext_vector_type(4), aligned(16)));  // aligned vec

__device__ __forceinline__ float readlane_f(float v, int l) {
    return __int_as_float(__builtin_amdgcn_readlane(__float_as_int(v), l));
}
// lane i <- lane i-1, via DPP wave_shr:1 (VALU-speed, replaces ds_bpermute)
__device__ __forceinline__ float shup1(float v) {
    return __int_as_float(__builtin_amdgcn_update_dpp(
        0, __float_as_int(v), 0x138, 0xF, 0xF, false));
}

// Lane-systolic DTW, R=4 rows/step, KC=4 cols/lane, 1-step lane stagger.
// MODE 1 (staged): raw tile -> stage[g][s][r][lane] (fully coalesced 1KB
// stores); sqrt + scatter into out[] done by a separate full-chip pass.
// MODE 0 (direct): raw f4a stores straight into out[]; in-place sqrt pass at
// the end. Cross-wave boundary carries staged raw in bnd (or read raw from
// out if bnd==null), 32 rows / flag, agent-scope release/acquire.
template <int MODE>
__global__ void __launch_bounds__(64) dtw_main(const float* __restrict__ x,
                                               const float* __restrict__ y,
                                               float* __restrict__ out,
                                               int* __restrict__ flags,
                                               float* __restrict__ bnd,
                                               float* __restrict__ stage) {
    const int g    = blockIdx.x;
    const int lane = threadIdx.x;
    const int j0   = g * WCH;
    const int c0   = j0 + lane * KC;

    float yv[KC], cur[KC];
#pragma unroll
    for (int q = 0; q < KC; ++q) {
        yv[q]  = y[c0 + q];
        cur[q] = FINF;                   // dtw[0][col] = INF
    }
    float pl = (c0 == 0) ? 0.0f : FINF;  // diag seed: dtw[0][0] = 0
    float rlast[R];
#pragma unroll
    for (int r = 0; r < R; ++r) rlast[r] = FINF;
    float vbuf = FINF;

    // x register window, double-buffered: x4[w*64+lane] = x[4*(w*64+lane)..+3]
    const float4* x4 = (const float4*)x;
    float4 xw  = x4[lane];
    float4 xwN = x4[64 + lane];
    float xcur[R];
#pragma unroll
    for (int r = 0; r < R; ++r) xcur[r] = x[r];

    float cnx[R][KC];                    // (x-y)^2 for the CURRENT step
#pragma unroll
    for (int r = 0; r < R; ++r)
#pragma unroll
        for (int q = 0; q < KC; ++q) {
            const float d = xcur[r] - yv[q];
            cnx[r][q] = d * d;
        }

    int off = (1 - R * lane) * MP1 + c0 + 1;   // direct-mode out offset

    for (int s = 0; s < STEPS; ++s) {
        // ---- consumer: fetch 32 left-boundary rows at tile start ----
        if (g != 0 && s < NWS && (s & (RTS - 1)) == 0) {
            const int want = (s >> 3) + 1;
            while (__hip_atomic_load(&flags[(g - 1) * 16], __ATOMIC_ACQUIRE,
                                     __HIP_MEMORY_SCOPE_AGENT) < want) {
                __builtin_amdgcn_s_sleep(1);
            }
            float tv = FINF;
            if (bnd) {
                if (lane < 32) tv = bnd[(size_t)(g - 1) * NN + R * s + lane];
            } else {
                if (lane < 32) tv = out[(size_t)(R * s + 1 + lane) * MP1 + j0];
            }
            vbuf = tv;
        }

        // ---- carries: DPP wave_shr1 of last step's right edges ----
        float vin[R];
#pragma unroll
        for (int r = 0; r < R; ++r) {
            const float up = shup1(rlast[r]);
            const float vb = readlane_f(vbuf, ((s & (RTS - 1)) << 2) + r);
            const float l0 = (g == 0) ? FINF : vb;
            vin[r] = (lane == 0) ? l0 : up;
        }

        const bool active = (s >= lane) && (s - lane < NWS);
        if (active) {
#pragma unroll
            for (int r = 0; r < R; ++r) {
                float rl  = vin[r];
                float pm1 = (r == 0) ? pl : vin[r - 1];
                float nv[KC];
#pragma unroll
                for (int q = 0; q < KC; ++q) {
                    const float upv = cur[q];
                    rl     = cnx[r][q] + fminf(fminf(rl, upv), pm1);
                    pm1    = upv;
                    cur[q] = rl;
                    nv[q]  = rl;
                }
                rlast[r] = rl;
                if (MODE == 1) {
                    float* sb = stage + (((size_t)(g * STEPS + s)) << 10);
                    *(f4v*)(sb + (r << 8) + (lane << 2)) =
                        (f4v){nv[0], nv[1], nv[2], nv[3]};
                } else {
                    *(f4a*)(&out[off + r * MP1]) =
                        (f4a){nv[0], nv[1], nv[2], nv[3]};
                }
            }
            pl = vin[R - 1];
            if (bnd && lane == 63) {
                *(f4a*)&bnd[(size_t)g * NN + R * (s - 63)] =
                    (f4a){rlast[0], rlast[1], rlast[2], rlast[3]};
            }
        }
        off += R * MP1;

        // ---- x for next step (off the carry chain) ----
        const int sn = s + 1;
        if ((sn & 63) == 0) {
            xw = xwN;
            int nb = sn + 64 + lane;
            if (nb > NN / 4 - 1) nb = NN / 4 - 1;
            xwN = x4[nb];
        }
        const float* xwp = (const float*)&xw;
#pragma unroll
        for (int r = 0; r < R; ++r) {
            const float xs = shup1(xcur[r]);
            const float xj = readlane_f(xwp[r], sn & 63);
            xcur[r] = (lane == 0) ? xj : xs;
        }
#pragma unroll
        for (int r = 0; r < R; ++r)
#pragma unroll
            for (int q = 0; q < KC; ++q) {
                const float d = xcur[r] - yv[q];
                cnx[r][q] = d * d;
            }

        // ---- producer: publish every 32 completed boundary rows ----
        if (g != GCH - 1 && s > 62 && ((s - 62) & (RTS - 1)) == 0) {
            __threadfence();
            if (lane == 0)
                __hip_atomic_store(&flags[g * 16], (s - 62) >> 3,
                                   __ATOMIC_RELEASE, __HIP_MEMORY_SCOPE_AGENT);
        }
    }
}

// Staged mode: read stage coalesced, sqrt, scatter 16B chunks into out.
// One 64-thread block per (g, s); lane l holds rows R*(s-l)+1..+4.
__global__ void __launch_bounds__(64) scatter_pass(const float* __restrict__ stage,
                                                   float* __restrict__ out) {
    const int b = blockIdx.x;            // b = g*STEPS + s
    const int g = b / STEPS;
    const int s = b - g * STEPS;
    const int l = threadIdx.x;
    const int t = s - l;
    if (t < 0 || t >= NWS) return;
    const float* sb = stage + (((size_t)b) << 10) + (l << 2);
    float* ob = out + (size_t)(R * t + 1) * MP1 + g * WCH + l * KC + 1;
#pragma unroll
    for (int r = 0; r < R; ++r) {
        f4v v = *(const f4v*)(sb + (r << 8));
        f4a o = {__builtin_amdgcn_sqrtf(v.x), __builtin_amdgcn_sqrtf(v.y),
                 __builtin_amdgcn_sqrtf(v.z), __builtin_amdgcn_sqrtf(v.w)};
        *(f4a*)(ob + r * MP1) = o;
    }
}

// Direct mode: in-place sqrt over the whole table (incl. raw edges).
__global__ void sqrt_inplace(float* __restrict__ out, int n4, long long total) {
    const int i = blockIdx.x * blockDim.x + threadIdx.x;
    if (i < n4) {
        f4v v = ((f4v*)out)[i];
        v = (f4v){__builtin_amdgcn_sqrtf(v.x), __builtin_amdgcn_sqrtf(v.y),
                  __builtin_amdgcn_sqrtf(v.z), __builtin_amdgcn_sqrtf(v.w)};
        ((f4v*)out)[i] = v;
    } else if (i == n4) {
        for (long long j = (long long)n4 * 4; j < total; ++j)
            out[j] = __builtin_amdgcn_sqrtf(out[j]);
    }
}

// Row 0 / column 0 sentinels; `ev` is INF (direct mode, sqrt'd later) or
// sqrt(INF) (staged mode, final).
__global__ void dtw_edges(float* __restrict__ out, float ev) {
    const int idx = blockIdx.x * blockDim.x + threadIdx.x;
    if (idx <= NN) {
        out[idx] = (idx == 0) ? 0.0f : ev;          // row 0
        if (idx >= 1) out[(size_t)idx * MP1] = ev;  // column 0
    }
}

extern "C" void kernel_launch(void* const* d_in, const int* in_sizes, int n_in,
                              void* d_out, int out_size, void* d_ws, size_t ws_size,
                              hipStream_t stream) {
    (void)in_sizes; (void)n_in; (void)out_size;
    const float* x = (const float*)d_in[0];
    const float* y = (const float*)d_in[1];
    float* out     = (float*)d_out;
    int* flags     = (int*)d_ws;

    const size_t bnd_off      = 4096;
    const size_t bnd_bytes    = (size_t)GCH * NN * sizeof(float);     // 576 KB
    const size_t stage_off    = bnd_off + bnd_bytes;                  // 593920
    const size_t stage_bytes  = (size_t)GCH * STEPS * 4096;           // ~150 MB
    const size_t stage_needed = stage_off + stage_bytes;

    float* bnd   = (ws_size >= stage_off) ? (float*)((char*)d_ws + bnd_off) : nullptr;
    float* stage = (ws_size >= stage_needed) ? (float*)((char*)d_ws + stage_off) : nullptr;

    hipMemsetAsync(flags, 0, GCH * 16 * sizeof(int), stream);

    const long long total = (long long)MP1 * MP1;   // 37,761,025
    const int n4 = (int)(total / 4);

    if (stage) {
        dtw_edges<<<(MP1 + 255) / 256, 256, 0, stream>>>(out, sqrtf(FINF));
        dtw_main<1><<<GCH, 64, 0, stream>>>(x, y, out, flags, bnd, stage);
        scatter_pass<<<GCH * STEPS, 64, 0, stream>>>(stage, out);
    } else {
        dtw_edges<<<(MP1 + 255) / 256, 256, 0, stream>>>(out, FINF);
        dtw_main<0><<<GCH, 64, 0, stream>>>(x, y, out, flags, bnd, nullptr);
        sqrt_inplace<<<(n4 + 256) / 256, 256, 0, stream>>>(out, n4, total);
    }
}